// Round 20
// baseline (291.842 us; speedup 1.0000x reference)
//
#include <hip/hip_runtime.h>
#include <hip/hip_bf16.h>
#include <math.h>

#define FEAT 96
#define ACTF 32

using frag8 = __attribute__((ext_vector_type(8))) short;   // 8 bf16 (4 VGPRs)
using f32x4 = __attribute__((ext_vector_type(4))) float;

__device__ __forceinline__ float lrelu(float x) { return x >= 0.f ? x : 0.2f * x; }
__device__ __forceinline__ void atomAddF(float* p, float v) {
    __hip_atomic_fetch_add(p, v, __ATOMIC_RELAXED, __HIP_MEMORY_SCOPE_AGENT);
}
__device__ __forceinline__ float expc(float x) { return __expf(fminf(x, 60.f)); }
__device__ __forceinline__ unsigned short f2bf(float f) {
    __hip_bfloat16 h = __float2bfloat16(f);
    return *(unsigned short*)&h;
}
__device__ __forceinline__ float bf2f(unsigned short u) {
    return __uint_as_float((unsigned)u << 16);
}
__device__ __forceinline__ float bflo(unsigned u) { return __uint_as_float(u << 16); }
__device__ __forceinline__ float bfhi(unsigned u) { return __uint_as_float(u & 0xffff0000u); }

// ---------- merged prep: xprep (vectorized, 8 elems/thread) + W1-fuse + W2 ----------
__global__ __launch_bounds__(256) void prep_all(
    const float* __restrict__ nf, const float* __restrict__ act,
    unsigned short* __restrict__ Xh, unsigned short* __restrict__ Xl,
    int N, int xb,
    const float* __restrict__ Wemb, const float* __restrict__ bemb,
    const float* __restrict__ W1,
    unsigned short* __restrict__ wfh, unsigned short* __restrict__ wfl,
    float* __restrict__ bfused,
    const float* __restrict__ W2, __hip_bfloat16* __restrict__ w2t) {
    int b = blockIdx.x;
    if (b < xb) {
        int gid = b * 256 + threadIdx.x;
        int node = gid >> 4, sub = gid & 15;
        if (node < N) {
            int k0 = sub * 8;
            float4 v0, v1;
            if (k0 < FEAT) {
                const float4* p = (const float4*)(nf + (size_t)node * FEAT + k0);
                v0 = p[0]; v1 = p[1];
            } else {
                const float4* p = (const float4*)(act + (size_t)node * ACTF + (k0 - FEAT));
                v0 = p[0]; v1 = p[1];
            }
            float vv[8] = {v0.x, v0.y, v0.z, v0.w, v1.x, v1.y, v1.z, v1.w};
            uint4 ph, pl;
            unsigned hs[8], ls[8];
            #pragma unroll
            for (int j = 0; j < 8; ++j) {
                unsigned short h = f2bf(vv[j]);
                hs[j] = h;
                ls[j] = f2bf(vv[j] - bf2f(h));
            }
            ph.x = hs[0] | (hs[1] << 16); ph.y = hs[2] | (hs[3] << 16);
            ph.z = hs[4] | (hs[5] << 16); ph.w = hs[6] | (hs[7] << 16);
            pl.x = ls[0] | (ls[1] << 16); pl.y = ls[2] | (ls[3] << 16);
            pl.z = ls[4] | (ls[5] << 16); pl.w = ls[6] | (ls[7] << 16);
            size_t idx = (size_t)node * 128 + k0;
            *(uint4*)(Xh + idx) = ph;
            *(uint4*)(Xl + idx) = pl;
        }
        return;
    }
    b -= xb;
    if (b < 129) {
        int k = b, c = threadIdx.x;
        if (k < 128) {
            float s = 0.f;
            for (int j = 0; j < 64; ++j) s = fmaf(Wemb[k * 64 + j], W1[j * 256 + c], s);
            unsigned short h = f2bf(s);
            wfh[(size_t)c * 128 + k] = h;
            wfl[(size_t)c * 128 + k] = f2bf(s - bf2f(h));
        } else {
            float s = 0.f;
            for (int j = 0; j < 64; ++j) s = fmaf(bemb[j], W1[j * 256 + c], s);
            bfused[c] = s;
        }
        return;
    }
    b -= 129;
    int i = b * 256 + threadIdx.x;
    int k = i >> 6, c = i & 63;
    w2t[(size_t)c * 256 + k] = __float2bfloat16(W2[i]);
}

// ---------- GEMM1 via MFMA + merged hist; A software-pipelined ----------
// Blocks [0,gb): split-bf16 MFMA GEMM, B-in-register, ct split by wave,
//   with next-tile A prefetch hidden under current tile's compute.
// Blocks [gb,..): edge histogram (independent data; overlaps GEMM).
__global__ __launch_bounds__(256, 2) void gemm1_hist(
    const unsigned short* __restrict__ Xh, const unsigned short* __restrict__ Xl,
    const unsigned short* __restrict__ wfh, const unsigned short* __restrict__ wfl,
    const float* __restrict__ bfused, const float* __restrict__ att_s,
    const float* __restrict__ att_d, __hip_bfloat16* __restrict__ h1b,
    float* __restrict__ a_s, float* __restrict__ a_d, int N,
    const int* __restrict__ dstp, int* __restrict__ cnt, int E, int ET, int gb) {
    if (blockIdx.x >= gb) {
        int e = (blockIdx.x - gb) * 256 + threadIdx.x;
        if (e < ET) {
            int d = (e < E) ? dstp[e] : (e - E);
            atomicAdd(&cnt[d], 1);
        }
        return;
    }
    int w = threadIdx.x >> 6, l = threadIdx.x & 63;
    int r16 = l & 15, kg = l >> 4;
    frag8 bh[4][4], bl[4][4];
    #pragma unroll
    for (int c = 0; c < 4; ++c) {
        int ct = w * 4 + c;
        const short* bhp = (const short*)wfh + (size_t)(ct * 16 + r16) * 128 + kg * 8;
        const short* blp = (const short*)wfl + (size_t)(ct * 16 + r16) * 128 + kg * 8;
        #pragma unroll
        for (int ks = 0; ks < 4; ++ks) {
            bh[c][ks] = *(const frag8*)(bhp + ks * 32);
            bl[c][ks] = *(const frag8*)(blp + ks * 32);
        }
    }
    float biasv[4], awv[4], dwv[4];
    #pragma unroll
    for (int c = 0; c < 4; ++c) {
        int ch = w * 64 + c * 16 + r16;
        biasv[c] = bfused[ch];
        awv[c] = att_s[ch];
        dwv[c] = att_d[ch];
    }
    int ntiles = (N + 15) >> 4;
    int tile = blockIdx.x;
    if (tile >= ntiles) return;
    frag8 ah[4], al[4];
    {   // prologue A-load
        int arow = tile * 16 + r16; if (arow >= N) arow = N - 1;
        const short* ahp = (const short*)Xh + (size_t)arow * 128 + kg * 8;
        const short* alp = (const short*)Xl + (size_t)arow * 128 + kg * 8;
        #pragma unroll
        for (int ks = 0; ks < 4; ++ks) {
            ah[ks] = *(const frag8*)(ahp + ks * 32);
            al[ks] = *(const frag8*)(alp + ks * 32);
        }
    }
    for (; tile < ntiles; tile += gb) {
        int nb = tile * 16;
        // prefetch next tile's A while this tile computes
        frag8 nah[4], nal[4];
        int ntile = tile + gb;
        if (ntile < ntiles) {
            int arow = ntile * 16 + r16; if (arow >= N) arow = N - 1;
            const short* ahp = (const short*)Xh + (size_t)arow * 128 + kg * 8;
            const short* alp = (const short*)Xl + (size_t)arow * 128 + kg * 8;
            #pragma unroll
            for (int ks = 0; ks < 4; ++ks) {
                nah[ks] = *(const frag8*)(ahp + ks * 32);
                nal[ks] = *(const frag8*)(alp + ks * 32);
            }
        }
        float s_s[4] = {0.f, 0.f, 0.f, 0.f}, s_d[4] = {0.f, 0.f, 0.f, 0.f};
        #pragma unroll
        for (int c = 0; c < 4; ++c) {
            f32x4 acc = (f32x4){0.f, 0.f, 0.f, 0.f};
            #pragma unroll
            for (int ks = 0; ks < 4; ++ks) {
                acc = __builtin_amdgcn_mfma_f32_16x16x32_bf16(ah[ks], bh[c][ks], acc, 0, 0, 0);
                acc = __builtin_amdgcn_mfma_f32_16x16x32_bf16(al[ks], bh[c][ks], acc, 0, 0, 0);
                acc = __builtin_amdgcn_mfma_f32_16x16x32_bf16(ah[ks], bl[c][ks], acc, 0, 0, 0);
            }
            int ch = w * 64 + c * 16 + r16;
            #pragma unroll
            for (int r = 0; r < 4; ++r) {
                int node = nb + kg * 4 + r;
                float v = acc[r] + biasv[c];
                if (node < N) h1b[(size_t)node * 256 + ch] = __float2bfloat16(v);
                s_s[r] = fmaf(v, awv[c], s_s[r]);
                s_d[r] = fmaf(v, dwv[c], s_d[r]);
            }
        }
        #pragma unroll
        for (int r = 0; r < 4; ++r) {
            float vs = s_s[r], vd = s_d[r];
            #pragma unroll
            for (int o = 1; o < 16; o <<= 1) {
                vs += __shfl_xor(vs, o);
                vd += __shfl_xor(vd, o);
            }
            int node = nb + kg * 4 + r;
            if (r16 == 0 && node < N) {
                a_s[(size_t)node * 4 + w] = vs;
                a_d[(size_t)node * 4 + w] = vd;
            }
        }
        #pragma unroll
        for (int ks = 0; ks < 4; ++ks) { ah[ks] = nah[ks]; al[ks] = nal[ks]; }
    }
}

// ---------- GEMM2 via MFMA: B-in-register, grid-stride ----------
__global__ __launch_bounds__(256, 2) void gemm2_mfma_w(
    const __hip_bfloat16* __restrict__ out1b, const __hip_bfloat16* __restrict__ w2t,
    const float* __restrict__ att_s, const float* __restrict__ att_d,
    __hip_bfloat16* __restrict__ h2b, float* __restrict__ a_s, float* __restrict__ a_d,
    int N) {
    int w = threadIdx.x >> 6, l = threadIdx.x & 63;
    int r16 = l & 15, kg = l >> 4;
    const short* B = (const short*)w2t;
    frag8 b[4][8];
    #pragma unroll
    for (int ct = 0; ct < 4; ++ct) {
        const short* brp = B + (size_t)(ct * 16 + r16) * 256 + kg * 8;
        #pragma unroll
        for (int ks = 0; ks < 8; ++ks)
            b[ct][ks] = *(const frag8*)(brp + ks * 32);
    }
    float awv[4], dwv[4];
    #pragma unroll
    for (int ct = 0; ct < 4; ++ct) {
        int ch = ct * 16 + r16;
        awv[ct] = att_s[ch];
        dwv[ct] = att_d[ch];
    }
    const short* A = (const short*)out1b;
    int ntiles = (N + 15) >> 4;
    for (int tile = blockIdx.x * 4 + w; tile < ntiles; tile += gridDim.x * 4) {
        int nb = tile * 16;
        int arow = nb + r16; if (arow >= N) arow = N - 1;
        const short* arp = A + (size_t)arow * 256 + kg * 8;
        frag8 a[8];
        #pragma unroll
        for (int ks = 0; ks < 8; ++ks) a[ks] = *(const frag8*)(arp + ks * 32);
        float s_s[4] = {0.f, 0.f, 0.f, 0.f}, s_d[4] = {0.f, 0.f, 0.f, 0.f};
        #pragma unroll
        for (int ct = 0; ct < 4; ++ct) {
            f32x4 acc = (f32x4){0.f, 0.f, 0.f, 0.f};
            #pragma unroll
            for (int ks = 0; ks < 8; ++ks)
                acc = __builtin_amdgcn_mfma_f32_16x16x32_bf16(a[ks], b[ct][ks], acc, 0, 0, 0);
            int ch = ct * 16 + r16;
            #pragma unroll
            for (int r = 0; r < 4; ++r) {
                int node = nb + kg * 4 + r;
                float v = acc[r];
                if (node < N) h2b[(size_t)node * 64 + ch] = __float2bfloat16(v);
                s_s[r] = fmaf(v, awv[ct], s_s[r]);
                s_d[r] = fmaf(v, dwv[ct], s_d[r]);
            }
        }
        #pragma unroll
        for (int r = 0; r < 4; ++r) {
            #pragma unroll
            for (int o = 1; o < 16; o <<= 1) {
                s_s[r] += __shfl_xor(s_s[r], o);
                s_d[r] += __shfl_xor(s_d[r], o);
            }
            int node = nb + kg * 4 + r;
            if (r16 == 0 && node < N) { a_s[node] = s_s[r]; a_d[node] = s_d[r]; }
        }
    }
}

// ---------- hierarchical scan ----------
__global__ __launch_bounds__(256) void scan_blocks(
    const int* __restrict__ cnt, int* __restrict__ offl, int* __restrict__ bsum, int n) {
    int b = blockIdx.x, t = threadIdx.x;
    int i = b * 256 + t;
    int v = (i < n) ? cnt[i] : 0;
    int lane = t & 63, w = t >> 6;
    int x = v;
    #pragma unroll
    for (int o = 1; o < 64; o <<= 1) {
        int y = __shfl_up(x, o);
        if (lane >= o) x += y;
    }
    __shared__ int wtot[4];
    if (lane == 63) wtot[w] = x;
    __syncthreads();
    int add = 0;
    #pragma unroll
    for (int j = 0; j < 4; ++j) if (j < w) add += wtot[j];
    int incl = x + add;
    if (i < n) offl[i] = incl - v;    // exclusive prefix within block
    if (t == 255) bsum[b] = incl;
}

// also zeroes g[64] + done counter for colsum_final
__global__ __launch_bounds__(256) void scan_tops(
    const int* __restrict__ bsum, int* __restrict__ bpre, int nb,
    float* __restrict__ g, int* __restrict__ done) {
    int t = threadIdx.x;
    int v = (t < nb) ? bsum[t] : 0;
    int lane = t & 63, w = t >> 6;
    int x = v;
    #pragma unroll
    for (int o = 1; o < 64; o <<= 1) {
        int y = __shfl_up(x, o);
        if (lane >= o) x += y;
    }
    __shared__ int wtot[4];
    if (lane == 63) wtot[w] = x;
    __syncthreads();
    int add = 0;
    #pragma unroll
    for (int j = 0; j < 4; ++j) if (j < w) add += wtot[j];
    if (t < nb) bpre[t] = x + add - v;
    if (t == 255) bpre[nb] = x + add;
    if (t < 64) g[t] = 0.f;
    if (t == 64) *done = 0;
}

// ---------- scatter + off-finalize (merged; independent block roles) ----------
__global__ void scatter_fin(const int* __restrict__ src, const int* __restrict__ dst,
                            const int* __restrict__ offl, const int* __restrict__ bpre,
                            int* __restrict__ cur, int* __restrict__ perm,
                            int* __restrict__ off, int E, int ET, int n, int nb, int sb) {
    if (blockIdx.x < sb) {
        int e = blockIdx.x * 256 + threadIdx.x;
        if (e >= ET) return;
        int s = (e < E) ? src[e] : (e - E);
        int d = (e < E) ? dst[e] : (e - E);
        int r = atomicAdd(&cur[d], 1);
        perm[offl[d] + bpre[d >> 8] + r] = s;
    } else {
        int i = (blockIdx.x - sb) * 256 + threadIdx.x;
        if (i < n) off[i] = offl[i] + bpre[i >> 8];
        if (i == n) off[n] = bpre[nb];
    }
}

// ---------- fused GAT layer 1 (H=4): single pass, den fused into staging ----------
__global__ __launch_bounds__(256) void fused_gat4(
    const int* __restrict__ off, const int* __restrict__ perm,
    const float* __restrict__ a_s, const float* __restrict__ a_d,
    const __hip_bfloat16* __restrict__ h1b, const float* __restrict__ bias,
    __hip_bfloat16* __restrict__ out1b, int N) {
    __shared__ float exls[4][4][68];
    __shared__ unsigned idxls[4][64];
    int w = threadIdx.x >> 6, l = threadIdx.x & 63;
    int d = blockIdx.x * 4 + w;
    if (d >= N) return;
    int lo = off[d], hi = off[d + 1];
    const float4* as4 = (const float4*)a_s;
    float4 ad = ((const float4*)a_d)[d];
    int eg = l >> 5;
    int li = l & 31;
    int gh = li >> 3;
    const char* hb = (const char*)h1b;
    unsigned laneoff = (unsigned)li * 16u;
    float acc[8] = {0.f, 0.f, 0.f, 0.f, 0.f, 0.f, 0.f, 0.f};
    float dx = 0.f, dy = 0.f, dz = 0.f, dw = 0.f;
    for (int base = lo; base < hi; base += 64) {
        int e = base + l;
        bool valid = e < hi;
        int s = valid ? perm[e] : 0;
        float4 a = as4[s];
        float e0 = valid ? expc(lrelu(a.x + ad.x)) : 0.f;
        float e1 = valid ? expc(lrelu(a.y + ad.y)) : 0.f;
        float e2 = valid ? expc(lrelu(a.z + ad.z)) : 0.f;
        float e3 = valid ? expc(lrelu(a.w + ad.w)) : 0.f;
        dx += e0; dy += e1; dz += e2; dw += e3;
        exls[w][0][l] = e0;
        exls[w][1][l] = e1;
        exls[w][2][l] = e2;
        exls[w][3][l] = e3;
        idxls[w][l] = valid ? (unsigned)s * 512u : 0u;
        int n = min(64, hi - base);
        #pragma unroll 2
        for (int i = 0; i < n; i += 2) {
            int ii = i + eg;
            float ex = exls[w][gh][ii];
            unsigned voff = idxls[w][ii] + laneoff;
            uint4 v = *(const uint4*)(hb + voff);
            acc[0] = fmaf(ex, bflo(v.x), acc[0]);
            acc[1] = fmaf(ex, bfhi(v.x), acc[1]);
            acc[2] = fmaf(ex, bflo(v.y), acc[2]);
            acc[3] = fmaf(ex, bfhi(v.y), acc[3]);
            acc[4] = fmaf(ex, bflo(v.z), acc[4]);
            acc[5] = fmaf(ex, bfhi(v.z), acc[5]);
            acc[6] = fmaf(ex, bflo(v.w), acc[6]);
            acc[7] = fmaf(ex, bfhi(v.w), acc[7]);
        }
    }
    #pragma unroll
    for (int o = 32; o; o >>= 1) {
        dx += __shfl_xor(dx, o); dy += __shfl_xor(dy, o);
        dz += __shfl_xor(dz, o); dw += __shfl_xor(dw, o);
    }
    float rr = 1.f / ((gh == 0 ? dx : gh == 1 ? dy : gh == 2 ? dz : dw) + 1e-16f);
    #pragma unroll
    for (int j = 0; j < 8; ++j) acc[j] += __shfl_xor(acc[j], 32);
    if (eg == 0) {
        float4 b0 = ((const float4*)bias)[li * 2];
        float4 b1 = ((const float4*)bias)[li * 2 + 1];
        uint4 pk;
        pk.x = (unsigned)f2bf(fmaxf(fmaf(acc[0], rr, b0.x), 0.f))
             | ((unsigned)f2bf(fmaxf(fmaf(acc[1], rr, b0.y), 0.f)) << 16);
        pk.y = (unsigned)f2bf(fmaxf(fmaf(acc[2], rr, b0.z), 0.f))
             | ((unsigned)f2bf(fmaxf(fmaf(acc[3], rr, b0.w), 0.f)) << 16);
        pk.z = (unsigned)f2bf(fmaxf(fmaf(acc[4], rr, b1.x), 0.f))
             | ((unsigned)f2bf(fmaxf(fmaf(acc[5], rr, b1.y), 0.f)) << 16);
        pk.w = (unsigned)f2bf(fmaxf(fmaf(acc[6], rr, b1.z), 0.f))
             | ((unsigned)f2bf(fmaxf(fmaf(acc[7], rr, b1.w), 0.f)) << 16);
        ((uint4*)(out1b + (size_t)d * 256))[li] = pk;
    }
}

// ---------- fused GAT layer 2 (H=1): single pass, den fused into staging ----------
__global__ __launch_bounds__(256) void fused_gat1(
    const int* __restrict__ off, const int* __restrict__ perm,
    const float* __restrict__ a_s, const float* __restrict__ a_d,
    const __hip_bfloat16* __restrict__ h2b, const float* __restrict__ bias,
    float* __restrict__ out2, int N) {
    __shared__ float exls1[4][64];
    __shared__ unsigned idxls1[4][64];
    int w = threadIdx.x >> 6, l = threadIdx.x & 63;
    int d = blockIdx.x * 4 + w;
    if (d >= N) return;
    int lo = off[d], hi = off[d + 1];
    float add = a_d[d];
    int eg = l >> 4;
    int li = l & 15;
    const char* hb = (const char*)h2b;
    unsigned laneoff = (unsigned)li * 8u;
    float den = 0.f;
    float acc0 = 0.f, acc1 = 0.f, acc2 = 0.f, acc3 = 0.f;
    for (int base = lo; base < hi; base += 64) {
        int e = base + l;
        bool valid = e < hi;
        int s = valid ? perm[e] : 0;
        float ex = valid ? expc(lrelu(a_s[s] + add)) : 0.f;
        den += ex;
        exls1[w][l] = ex;
        idxls1[w][l] = valid ? (unsigned)s * 128u : 0u;
        int n = min(64, hi - base);
        #pragma unroll 4
        for (int i = 0; i < n; i += 4) {
            int ii = i + eg;
            float exx = exls1[w][ii];
            unsigned voff = idxls1[w][ii] + laneoff;
            uint2 v = *(const uint2*)(hb + voff);
            acc0 = fmaf(exx, bflo(v.x), acc0);
            acc1 = fmaf(exx, bfhi(v.x), acc1);
            acc2 = fmaf(exx, bflo(v.y), acc2);
            acc3 = fmaf(exx, bfhi(v.y), acc3);
        }
    }
    #pragma unroll
    for (int o = 32; o; o >>= 1) den += __shfl_xor(den, o);
    float rr = 1.f / (den + 1e-16f);
    #pragma unroll
    for (int o = 16; o < 64; o <<= 1) {
        acc0 += __shfl_xor(acc0, o);
        acc1 += __shfl_xor(acc1, o);
        acc2 += __shfl_xor(acc2, o);
        acc3 += __shfl_xor(acc3, o);
    }
    if (eg == 0 && (l >> 4) == 0) {
        const float4* b4 = (const float4*)bias;
        float4 bv = b4[li];
        float4 o4;
        o4.x = fmaxf(fmaf(acc0, rr, bv.x), 0.f);
        o4.y = fmaxf(fmaf(acc1, rr, bv.y), 0.f);
        o4.z = fmaxf(fmaf(acc2, rr, bv.z), 0.f);
        o4.w = fmaxf(fmaf(acc3, rr, bv.w), 0.f);
        ((float4*)(out2 + (size_t)d * 64))[li] = o4;
    }
}

// ---------- column sum + final dot (merged via done-counter) ----------
__global__ __launch_bounds__(256) void colsum_final(
    const float* __restrict__ x, float* __restrict__ g, int* __restrict__ done,
    const float* __restrict__ Wv, const float* __restrict__ bv,
    float* __restrict__ out, int N) {
    __shared__ float part[4][64];
    __shared__ int amlast;
    int c = threadIdx.x & 63;
    int r = threadIdx.x >> 6;
    float acc = 0.f;
    for (long long n = (long long)blockIdx.x * 4 + r; n < N; n += (long long)gridDim.x * 4)
        acc += x[n * 64 + c];
    part[r][c] = acc;
    __syncthreads();
    if (r == 0) {
        float v = part[0][c] + part[1][c] + part[2][c] + part[3][c];
        atomAddF(&g[c], v);
    }
    __threadfence();
    if (threadIdx.x == 0) {
        int t = __hip_atomic_fetch_add(done, 1, __ATOMIC_ACQ_REL, __HIP_MEMORY_SCOPE_AGENT);
        amlast = (t == (int)gridDim.x - 1) ? 1 : 0;
    }
    __syncthreads();
    if (amlast && threadIdx.x < 64) {
        float gc = __hip_atomic_load(&g[threadIdx.x], __ATOMIC_RELAXED, __HIP_MEMORY_SCOPE_AGENT);
        float v = (gc / (float)N) * Wv[threadIdx.x];
        #pragma unroll
        for (int o = 32; o; o >>= 1) v += __shfl_down(v, o);
        if (threadIdx.x == 0) out[0] = v + bv[0];
    }
}

extern "C" void kernel_launch(void* const* d_in, const int* in_sizes, int n_in,
                              void* d_out, int out_size, void* d_ws, size_t ws_size,
                              hipStream_t stream) {
    const float* nf   = (const float*)d_in[0];
    const float* act  = (const float*)d_in[1];
    const int*   ei   = (const int*)d_in[2];
    const float* Wemb = (const float*)d_in[3];
    const float* bemb = (const float*)d_in[4];
    const float* W1   = (const float*)d_in[5];
    const float* as1  = (const float*)d_in[6];
    const float* ad1  = (const float*)d_in[7];
    const float* b1   = (const float*)d_in[8];
    const float* W2   = (const float*)d_in[9];
    const float* as2  = (const float*)d_in[10];
    const float* ad2  = (const float*)d_in[11];
    const float* b2   = (const float*)d_in[12];
    const float* Wv   = (const float*)d_in[13];
    const float* bv   = (const float*)d_in[14];
    float* out = (float*)d_out;

    const int N = in_sizes[0] / FEAT;
    const int E = in_sizes[2] / 2;
    const int ET = E + N;
    const int* srcp = ei;
    const int* dstp = ei + E;
    const int NB = (N + 255) / 256;
    const int HB = (ET + 255) / 256;

    // ---- workspace layout ----
    char* ws = (char*)d_ws;
    unsigned short* Xh = (unsigned short*)ws;                         // N*128 bf16
    unsigned short* Xl = Xh + (size_t)N * 128;                        // N*128 bf16
    __hip_bfloat16* h1b   = (__hip_bfloat16*)(Xl + (size_t)N * 128);  // N*256 bf16
    __hip_bfloat16* out1b = h1b + (size_t)N * 256;                    // N*256 bf16
    float* a_s  = (float*)(out1b + (size_t)N * 256);                  // N*4 f32
    float* a_d  = a_s + (size_t)N * 4;                                // N*4 f32
    __hip_bfloat16* h2b = (__hip_bfloat16*)(a_d + (size_t)N * 4);     // N*64 bf16
    float* out2 = (float*)(h2b + (size_t)N * 64);                     // N*64 f32
    float* g    = out2 + (size_t)N * 64;                              // 64
    __hip_bfloat16* w2t = (__hip_bfloat16*)(g + 64);                  // 64*256 bf16
    unsigned short* wfh = (unsigned short*)(w2t + 64 * 256);          // 256*128
    unsigned short* wfl = wfh + 256 * 128;                            // 256*128
    float* bfused = (float*)(wfl + 256 * 128);                        // 256 f32
    // CSR in dedicated region (no aliasing -> hist can overlap gemm1)
    int* cnt  = (int*)(bfused + 256);  // N
    int* cur  = cnt + N;               // N   (adjacent -> single memset)
    int* offl = cur + N;               // N   (block-local exclusive prefix)
    int* off  = offl + N;              // N+1 (finalized)
    int* perm = off + N + 1;           // ET
    int* bsum = perm + ET;             // NB
    int* bpre = bsum + NB;             // NB+1
    int* done = bpre + NB + 1;         // 1

    (void)ws_size; (void)n_in; (void)out_size;

    // ---- zero cnt+cur up front ----
    hipMemsetAsync(cnt, 0, (size_t)2 * N * sizeof(int), stream);

    // ---- merged prep: X split-bf16 (8 elems/thread) + fused W1 + W2 ----
    const int XB = ((N * 16) + 255) / 256;
    prep_all<<<XB + 129 + 64, 256, 0, stream>>>(nf, act, Xh, Xl, N, XB,
                                                Wemb, bemb, W1, wfh, wfl, bfused,
                                                W2, w2t);

    // ---- GAT layer 1 GEMM (MFMA, A-prefetch pipelined) + overlapped hist ----
    const int GB = 1024;
    gemm1_hist<<<GB + HB, 256, 0, stream>>>(Xh, Xl, wfh, wfl, bfused,
                                            as1, ad1, h1b, a_s, a_d, N,
                                            dstp, cnt, E, ET, GB);

    // ---- CSR scan + scatter ----
    scan_blocks<<<NB, 256, 0, stream>>>(cnt, offl, bsum, N);
    scan_tops<<<1, 256, 0, stream>>>(bsum, bpre, NB, g, done);
    {
        const int FB = (N + 1 + 255) / 256;
        scatter_fin<<<HB + FB, 256, 0, stream>>>(srcp, dstp, offl, bpre, cur,
                                                 perm, off, E, ET, N, NB, HB);
    }

    // ---- GAT layer 1: fused softmax + aggregate + bias + relu (bf16 out) ----
    fused_gat4<<<(N + 3) / 4, 256, 0, stream>>>(off, perm, a_s, a_d, h1b, b1, out1b, N);

    // ---- GAT layer 2: MFMA GEMM (B-in-register) + scores, then fused aggregate ----
    gemm2_mfma_w<<<512, 256, 0, stream>>>(out1b, w2t, as2, ad2, h2b, a_s, a_d, N);
    fused_gat1<<<(N + 3) / 4, 256, 0, stream>>>(off, perm, a_s, a_d, h2b, b2, out2, N);

    // ---- readout (merged colsum + final) ----
    colsum_final<<<512, 256, 0, stream>>>(out2, g, done, Wv, bv, out, N);
}

// Round 21
// 284.890 us; speedup vs baseline: 1.0244x; 1.0244x over previous
//
#include <hip/hip_runtime.h>
#include <hip/hip_bf16.h>
#include <math.h>

#define FEAT 96
#define ACTF 32

using frag8 = __attribute__((ext_vector_type(8))) short;   // 8 bf16 (4 VGPRs)
using f32x4 = __attribute__((ext_vector_type(4))) float;

__device__ __forceinline__ float lrelu(float x) { return x >= 0.f ? x : 0.2f * x; }
__device__ __forceinline__ void atomAddF(float* p, float v) {
    __hip_atomic_fetch_add(p, v, __ATOMIC_RELAXED, __HIP_MEMORY_SCOPE_AGENT);
}
__device__ __forceinline__ float expc(float x) { return __expf(fminf(x, 60.f)); }
__device__ __forceinline__ unsigned short f2bf(float f) {
    __hip_bfloat16 h = __float2bfloat16(f);
    return *(unsigned short*)&h;
}
__device__ __forceinline__ float bf2f(unsigned short u) {
    return __uint_as_float((unsigned)u << 16);
}
__device__ __forceinline__ float bflo(unsigned u) { return __uint_as_float(u << 16); }
__device__ __forceinline__ float bfhi(unsigned u) { return __uint_as_float(u & 0xffff0000u); }

// ---------- merged prep: xprep (vectorized, 8 elems/thread) + W1-fuse + W2 ----------
__global__ __launch_bounds__(256) void prep_all(
    const float* __restrict__ nf, const float* __restrict__ act,
    unsigned short* __restrict__ Xh, unsigned short* __restrict__ Xl,
    int N, int xb,
    const float* __restrict__ Wemb, const float* __restrict__ bemb,
    const float* __restrict__ W1,
    unsigned short* __restrict__ wfh, unsigned short* __restrict__ wfl,
    float* __restrict__ bfused,
    const float* __restrict__ W2, __hip_bfloat16* __restrict__ w2t) {
    int b = blockIdx.x;
    if (b < xb) {
        int gid = b * 256 + threadIdx.x;
        int node = gid >> 4, sub = gid & 15;
        if (node < N) {
            int k0 = sub * 8;
            float4 v0, v1;
            if (k0 < FEAT) {
                const float4* p = (const float4*)(nf + (size_t)node * FEAT + k0);
                v0 = p[0]; v1 = p[1];
            } else {
                const float4* p = (const float4*)(act + (size_t)node * ACTF + (k0 - FEAT));
                v0 = p[0]; v1 = p[1];
            }
            float vv[8] = {v0.x, v0.y, v0.z, v0.w, v1.x, v1.y, v1.z, v1.w};
            uint4 ph, pl;
            unsigned hs[8], ls[8];
            #pragma unroll
            for (int j = 0; j < 8; ++j) {
                unsigned short h = f2bf(vv[j]);
                hs[j] = h;
                ls[j] = f2bf(vv[j] - bf2f(h));
            }
            ph.x = hs[0] | (hs[1] << 16); ph.y = hs[2] | (hs[3] << 16);
            ph.z = hs[4] | (hs[5] << 16); ph.w = hs[6] | (hs[7] << 16);
            pl.x = ls[0] | (ls[1] << 16); pl.y = ls[2] | (ls[3] << 16);
            pl.z = ls[4] | (ls[5] << 16); pl.w = ls[6] | (ls[7] << 16);
            size_t idx = (size_t)node * 128 + k0;
            *(uint4*)(Xh + idx) = ph;
            *(uint4*)(Xl + idx) = pl;
        }
        return;
    }
    b -= xb;
    if (b < 129) {
        int k = b, c = threadIdx.x;
        if (k < 128) {
            float s = 0.f;
            for (int j = 0; j < 64; ++j) s = fmaf(Wemb[k * 64 + j], W1[j * 256 + c], s);
            unsigned short h = f2bf(s);
            wfh[(size_t)c * 128 + k] = h;
            wfl[(size_t)c * 128 + k] = f2bf(s - bf2f(h));
        } else {
            float s = 0.f;
            for (int j = 0; j < 64; ++j) s = fmaf(bemb[j], W1[j * 256 + c], s);
            bfused[c] = s;
        }
        return;
    }
    b -= 129;
    int i = b * 256 + threadIdx.x;
    int k = i >> 6, c = i & 63;
    w2t[(size_t)c * 256 + k] = __float2bfloat16(W2[i]);
}

// ---------- GEMM1 via MFMA + merged hist; A software-pipelined ----------
// Blocks [0,gb): split-bf16 MFMA GEMM, B-in-register, ct split by wave,
//   with next-tile A prefetch hidden under current tile's compute.
// Blocks [gb,..): edge histogram (independent data; overlaps GEMM).
__global__ __launch_bounds__(256, 2) void gemm1_hist(
    const unsigned short* __restrict__ Xh, const unsigned short* __restrict__ Xl,
    const unsigned short* __restrict__ wfh, const unsigned short* __restrict__ wfl,
    const float* __restrict__ bfused, const float* __restrict__ att_s,
    const float* __restrict__ att_d, __hip_bfloat16* __restrict__ h1b,
    float* __restrict__ a_s, float* __restrict__ a_d, int N,
    const int* __restrict__ dstp, int* __restrict__ cnt, int E, int ET, int gb) {
    if (blockIdx.x >= gb) {
        int e = (blockIdx.x - gb) * 256 + threadIdx.x;
        if (e < ET) {
            int d = (e < E) ? dstp[e] : (e - E);
            atomicAdd(&cnt[d], 1);
        }
        return;
    }
    int w = threadIdx.x >> 6, l = threadIdx.x & 63;
    int r16 = l & 15, kg = l >> 4;
    frag8 bh[4][4], bl[4][4];
    #pragma unroll
    for (int c = 0; c < 4; ++c) {
        int ct = w * 4 + c;
        const short* bhp = (const short*)wfh + (size_t)(ct * 16 + r16) * 128 + kg * 8;
        const short* blp = (const short*)wfl + (size_t)(ct * 16 + r16) * 128 + kg * 8;
        #pragma unroll
        for (int ks = 0; ks < 4; ++ks) {
            bh[c][ks] = *(const frag8*)(bhp + ks * 32);
            bl[c][ks] = *(const frag8*)(blp + ks * 32);
        }
    }
    float biasv[4], awv[4], dwv[4];
    #pragma unroll
    for (int c = 0; c < 4; ++c) {
        int ch = w * 64 + c * 16 + r16;
        biasv[c] = bfused[ch];
        awv[c] = att_s[ch];
        dwv[c] = att_d[ch];
    }
    int ntiles = (N + 15) >> 4;
    int tile = blockIdx.x;
    if (tile >= ntiles) return;
    frag8 ah[4], al[4];
    {   // prologue A-load
        int arow = tile * 16 + r16; if (arow >= N) arow = N - 1;
        const short* ahp = (const short*)Xh + (size_t)arow * 128 + kg * 8;
        const short* alp = (const short*)Xl + (size_t)arow * 128 + kg * 8;
        #pragma unroll
        for (int ks = 0; ks < 4; ++ks) {
            ah[ks] = *(const frag8*)(ahp + ks * 32);
            al[ks] = *(const frag8*)(alp + ks * 32);
        }
    }
    for (; tile < ntiles; tile += gb) {
        int nb = tile * 16;
        // prefetch next tile's A while this tile computes
        frag8 nah[4], nal[4];
        int ntile = tile + gb;
        if (ntile < ntiles) {
            int arow = ntile * 16 + r16; if (arow >= N) arow = N - 1;
            const short* ahp = (const short*)Xh + (size_t)arow * 128 + kg * 8;
            const short* alp = (const short*)Xl + (size_t)arow * 128 + kg * 8;
            #pragma unroll
            for (int ks = 0; ks < 4; ++ks) {
                nah[ks] = *(const frag8*)(ahp + ks * 32);
                nal[ks] = *(const frag8*)(alp + ks * 32);
            }
        }
        float s_s[4] = {0.f, 0.f, 0.f, 0.f}, s_d[4] = {0.f, 0.f, 0.f, 0.f};
        #pragma unroll
        for (int c = 0; c < 4; ++c) {
            f32x4 acc = (f32x4){0.f, 0.f, 0.f, 0.f};
            #pragma unroll
            for (int ks = 0; ks < 4; ++ks) {
                acc = __builtin_amdgcn_mfma_f32_16x16x32_bf16(ah[ks], bh[c][ks], acc, 0, 0, 0);
                acc = __builtin_amdgcn_mfma_f32_16x16x32_bf16(al[ks], bh[c][ks], acc, 0, 0, 0);
                acc = __builtin_amdgcn_mfma_f32_16x16x32_bf16(ah[ks], bl[c][ks], acc, 0, 0, 0);
            }
            int ch = w * 64 + c * 16 + r16;
            #pragma unroll
            for (int r = 0; r < 4; ++r) {
                int node = nb + kg * 4 + r;
                float v = acc[r] + biasv[c];
                if (node < N) h1b[(size_t)node * 256 + ch] = __float2bfloat16(v);
                s_s[r] = fmaf(v, awv[c], s_s[r]);
                s_d[r] = fmaf(v, dwv[c], s_d[r]);
            }
        }
        #pragma unroll
        for (int r = 0; r < 4; ++r) {
            float vs = s_s[r], vd = s_d[r];
            #pragma unroll
            for (int o = 1; o < 16; o <<= 1) {
                vs += __shfl_xor(vs, o);
                vd += __shfl_xor(vd, o);
            }
            int node = nb + kg * 4 + r;
            if (r16 == 0 && node < N) {
                a_s[(size_t)node * 4 + w] = vs;
                a_d[(size_t)node * 4 + w] = vd;
            }
        }
        #pragma unroll
        for (int ks = 0; ks < 4; ++ks) { ah[ks] = nah[ks]; al[ks] = nal[ks]; }
    }
}

// ---------- GEMM2 via MFMA: B-in-register, grid-stride ----------
__global__ __launch_bounds__(256, 2) void gemm2_mfma_w(
    const __hip_bfloat16* __restrict__ out1b, const __hip_bfloat16* __restrict__ w2t,
    const float* __restrict__ att_s, const float* __restrict__ att_d,
    __hip_bfloat16* __restrict__ h2b, float* __restrict__ a_s, float* __restrict__ a_d,
    int N) {
    int w = threadIdx.x >> 6, l = threadIdx.x & 63;
    int r16 = l & 15, kg = l >> 4;
    const short* B = (const short*)w2t;
    frag8 b[4][8];
    #pragma unroll
    for (int ct = 0; ct < 4; ++ct) {
        const short* brp = B + (size_t)(ct * 16 + r16) * 256 + kg * 8;
        #pragma unroll
        for (int ks = 0; ks < 8; ++ks)
            b[ct][ks] = *(const frag8*)(brp + ks * 32);
    }
    float awv[4], dwv[4];
    #pragma unroll
    for (int ct = 0; ct < 4; ++ct) {
        int ch = ct * 16 + r16;
        awv[ct] = att_s[ch];
        dwv[ct] = att_d[ch];
    }
    const short* A = (const short*)out1b;
    int ntiles = (N + 15) >> 4;
    for (int tile = blockIdx.x * 4 + w; tile < ntiles; tile += gridDim.x * 4) {
        int nb = tile * 16;
        int arow = nb + r16; if (arow >= N) arow = N - 1;
        const short* arp = A + (size_t)arow * 256 + kg * 8;
        frag8 a[8];
        #pragma unroll
        for (int ks = 0; ks < 8; ++ks) a[ks] = *(const frag8*)(arp + ks * 32);
        float s_s[4] = {0.f, 0.f, 0.f, 0.f}, s_d[4] = {0.f, 0.f, 0.f, 0.f};
        #pragma unroll
        for (int ct = 0; ct < 4; ++ct) {
            f32x4 acc = (f32x4){0.f, 0.f, 0.f, 0.f};
            #pragma unroll
            for (int ks = 0; ks < 8; ++ks)
                acc = __builtin_amdgcn_mfma_f32_16x16x32_bf16(a[ks], b[ct][ks], acc, 0, 0, 0);
            int ch = ct * 16 + r16;
            #pragma unroll
            for (int r = 0; r < 4; ++r) {
                int node = nb + kg * 4 + r;
                float v = acc[r];
                if (node < N) h2b[(size_t)node * 64 + ch] = __float2bfloat16(v);
                s_s[r] = fmaf(v, awv[ct], s_s[r]);
                s_d[r] = fmaf(v, dwv[ct], s_d[r]);
            }
        }
        #pragma unroll
        for (int r = 0; r < 4; ++r) {
            #pragma unroll
            for (int o = 1; o < 16; o <<= 1) {
                s_s[r] += __shfl_xor(s_s[r], o);
                s_d[r] += __shfl_xor(s_d[r], o);
            }
            int node = nb + kg * 4 + r;
            if (r16 == 0 && node < N) { a_s[node] = s_s[r]; a_d[node] = s_d[r]; }
        }
    }
}

// ---------- hierarchical scan ----------
__global__ __launch_bounds__(256) void scan_blocks(
    const int* __restrict__ cnt, int* __restrict__ offl, int* __restrict__ bsum, int n) {
    int b = blockIdx.x, t = threadIdx.x;
    int i = b * 256 + t;
    int v = (i < n) ? cnt[i] : 0;
    int lane = t & 63, w = t >> 6;
    int x = v;
    #pragma unroll
    for (int o = 1; o < 64; o <<= 1) {
        int y = __shfl_up(x, o);
        if (lane >= o) x += y;
    }
    __shared__ int wtot[4];
    if (lane == 63) wtot[w] = x;
    __syncthreads();
    int add = 0;
    #pragma unroll
    for (int j = 0; j < 4; ++j) if (j < w) add += wtot[j];
    int incl = x + add;
    if (i < n) offl[i] = incl - v;    // exclusive prefix within block
    if (t == 255) bsum[b] = incl;
}

// also zeroes g[64] + done counter for colsum_final
__global__ __launch_bounds__(256) void scan_tops(
    const int* __restrict__ bsum, int* __restrict__ bpre, int nb,
    float* __restrict__ g, int* __restrict__ done) {
    int t = threadIdx.x;
    int v = (t < nb) ? bsum[t] : 0;
    int lane = t & 63, w = t >> 6;
    int x = v;
    #pragma unroll
    for (int o = 1; o < 64; o <<= 1) {
        int y = __shfl_up(x, o);
        if (lane >= o) x += y;
    }
    __shared__ int wtot[4];
    if (lane == 63) wtot[w] = x;
    __syncthreads();
    int add = 0;
    #pragma unroll
    for (int j = 0; j < 4; ++j) if (j < w) add += wtot[j];
    if (t < nb) bpre[t] = x + add - v;
    if (t == 255) bpre[nb] = x + add;
    if (t < 64) g[t] = 0.f;
    if (t == 64) *done = 0;
}

// ---------- scatter + off-finalize (merged; independent block roles) ----------
__global__ void scatter_fin(const int* __restrict__ src, const int* __restrict__ dst,
                            const int* __restrict__ offl, const int* __restrict__ bpre,
                            int* __restrict__ cur, int* __restrict__ perm,
                            int* __restrict__ off, int E, int ET, int n, int nb, int sb) {
    if (blockIdx.x < sb) {
        int e = blockIdx.x * 256 + threadIdx.x;
        if (e >= ET) return;
        int s = (e < E) ? src[e] : (e - E);
        int d = (e < E) ? dst[e] : (e - E);
        int r = atomicAdd(&cur[d], 1);
        perm[offl[d] + bpre[d >> 8] + r] = s;
    } else {
        int i = (blockIdx.x - sb) * 256 + threadIdx.x;
        if (i < n) off[i] = offl[i] + bpre[i >> 8];
        if (i == n) off[n] = bpre[nb];
    }
}

// ---------- fused GAT layer 1 (H=4): single pass, den fused into staging ----------
__global__ __launch_bounds__(256) void fused_gat4(
    const int* __restrict__ off, const int* __restrict__ perm,
    const float* __restrict__ a_s, const float* __restrict__ a_d,
    const __hip_bfloat16* __restrict__ h1b, const float* __restrict__ bias,
    __hip_bfloat16* __restrict__ out1b, int N) {
    __shared__ float exls[4][4][68];
    __shared__ unsigned idxls[4][64];
    int w = threadIdx.x >> 6, l = threadIdx.x & 63;
    int d = blockIdx.x * 4 + w;
    if (d >= N) return;
    int lo = off[d], hi = off[d + 1];
    const float4* as4 = (const float4*)a_s;
    float4 ad = ((const float4*)a_d)[d];
    int eg = l >> 5;
    int li = l & 31;
    int gh = li >> 3;
    const char* hb = (const char*)h1b;
    unsigned laneoff = (unsigned)li * 16u;
    float acc[8] = {0.f, 0.f, 0.f, 0.f, 0.f, 0.f, 0.f, 0.f};
    float dx = 0.f, dy = 0.f, dz = 0.f, dw = 0.f;
    for (int base = lo; base < hi; base += 64) {
        int e = base + l;
        bool valid = e < hi;
        int s = valid ? perm[e] : 0;
        float4 a = as4[s];
        float e0 = valid ? expc(lrelu(a.x + ad.x)) : 0.f;
        float e1 = valid ? expc(lrelu(a.y + ad.y)) : 0.f;
        float e2 = valid ? expc(lrelu(a.z + ad.z)) : 0.f;
        float e3 = valid ? expc(lrelu(a.w + ad.w)) : 0.f;
        dx += e0; dy += e1; dz += e2; dw += e3;
        exls[w][0][l] = e0;
        exls[w][1][l] = e1;
        exls[w][2][l] = e2;
        exls[w][3][l] = e3;
        idxls[w][l] = valid ? (unsigned)s * 512u : 0u;
        int n = min(64, hi - base);
        #pragma unroll 2
        for (int i = 0; i < n; i += 2) {
            int ii = i + eg;
            float ex = exls[w][gh][ii];
            unsigned voff = idxls[w][ii] + laneoff;
            uint4 v = *(const uint4*)(hb + voff);
            acc[0] = fmaf(ex, bflo(v.x), acc[0]);
            acc[1] = fmaf(ex, bfhi(v.x), acc[1]);
            acc[2] = fmaf(ex, bflo(v.y), acc[2]);
            acc[3] = fmaf(ex, bfhi(v.y), acc[3]);
            acc[4] = fmaf(ex, bflo(v.z), acc[4]);
            acc[5] = fmaf(ex, bfhi(v.z), acc[5]);
            acc[6] = fmaf(ex, bflo(v.w), acc[6]);
            acc[7] = fmaf(ex, bfhi(v.w), acc[7]);
        }
    }
    #pragma unroll
    for (int o = 32; o; o >>= 1) {
        dx += __shfl_xor(dx, o); dy += __shfl_xor(dy, o);
        dz += __shfl_xor(dz, o); dw += __shfl_xor(dw, o);
    }
    float rr = 1.f / ((gh == 0 ? dx : gh == 1 ? dy : gh == 2 ? dz : dw) + 1e-16f);
    #pragma unroll
    for (int j = 0; j < 8; ++j) acc[j] += __shfl_xor(acc[j], 32);
    if (eg == 0) {
        float4 b0 = ((const float4*)bias)[li * 2];
        float4 b1 = ((const float4*)bias)[li * 2 + 1];
        uint4 pk;
        pk.x = (unsigned)f2bf(fmaxf(fmaf(acc[0], rr, b0.x), 0.f))
             | ((unsigned)f2bf(fmaxf(fmaf(acc[1], rr, b0.y), 0.f)) << 16);
        pk.y = (unsigned)f2bf(fmaxf(fmaf(acc[2], rr, b0.z), 0.f))
             | ((unsigned)f2bf(fmaxf(fmaf(acc[3], rr, b0.w), 0.f)) << 16);
        pk.z = (unsigned)f2bf(fmaxf(fmaf(acc[4], rr, b1.x), 0.f))
             | ((unsigned)f2bf(fmaxf(fmaf(acc[5], rr, b1.y), 0.f)) << 16);
        pk.w = (unsigned)f2bf(fmaxf(fmaf(acc[6], rr, b1.z), 0.f))
             | ((unsigned)f2bf(fmaxf(fmaf(acc[7], rr, b1.w), 0.f)) << 16);
        ((uint4*)(out1b + (size_t)d * 256))[li] = pk;
    }
}

// ---------- fused GAT layer 2 (H=1): single pass, den fused into staging ----------
__global__ __launch_bounds__(256) void fused_gat1(
    const int* __restrict__ off, const int* __restrict__ perm,
    const float* __restrict__ a_s, const float* __restrict__ a_d,
    const __hip_bfloat16* __restrict__ h2b, const float* __restrict__ bias,
    float* __restrict__ out2, int N) {
    __shared__ float exls1[4][64];
    __shared__ unsigned idxls1[4][64];
    int w = threadIdx.x >> 6, l = threadIdx.x & 63;
    int d = blockIdx.x * 4 + w;
    if (d >= N) return;
    int lo = off[d], hi = off[d + 1];
    float add = a_d[d];
    int eg = l >> 4;
    int li = l & 15;
    const char* hb = (const char*)h2b;
    unsigned laneoff = (unsigned)li * 8u;
    float den = 0.f;
    float acc0 = 0.f, acc1 = 0.f, acc2 = 0.f, acc3 = 0.f;
    for (int base = lo; base < hi; base += 64) {
        int e = base + l;
        bool valid = e < hi;
        int s = valid ? perm[e] : 0;
        float ex = valid ? expc(lrelu(a_s[s] + add)) : 0.f;
        den += ex;
        exls1[w][l] = ex;
        idxls1[w][l] = valid ? (unsigned)s * 128u : 0u;
        int n = min(64, hi - base);
        #pragma unroll 4
        for (int i = 0; i < n; i += 4) {
            int ii = i + eg;
            float exx = exls1[w][ii];
            unsigned voff = idxls1[w][ii] + laneoff;
            uint2 v = *(const uint2*)(hb + voff);
            acc0 = fmaf(exx, bflo(v.x), acc0);
            acc1 = fmaf(exx, bfhi(v.x), acc1);
            acc2 = fmaf(exx, bflo(v.y), acc2);
            acc3 = fmaf(exx, bfhi(v.y), acc3);
        }
    }
    #pragma unroll
    for (int o = 32; o; o >>= 1) den += __shfl_xor(den, o);
    float rr = 1.f / (den + 1e-16f);
    #pragma unroll
    for (int o = 16; o < 64; o <<= 1) {
        acc0 += __shfl_xor(acc0, o);
        acc1 += __shfl_xor(acc1, o);
        acc2 += __shfl_xor(acc2, o);
        acc3 += __shfl_xor(acc3, o);
    }
    if (eg == 0 && (l >> 4) == 0) {
        const float4* b4 = (const float4*)bias;
        float4 bv = b4[li];
        float4 o4;
        o4.x = fmaxf(fmaf(acc0, rr, bv.x), 0.f);
        o4.y = fmaxf(fmaf(acc1, rr, bv.y), 0.f);
        o4.z = fmaxf(fmaf(acc2, rr, bv.z), 0.f);
        o4.w = fmaxf(fmaf(acc3, rr, bv.w), 0.f);
        ((float4*)(out2 + (size_t)d * 64))[li] = o4;
    }
}

// ---------- column sum + final dot (merged via done-counter) ----------
__global__ __launch_bounds__(256) void colsum_final(
    const float* __restrict__ x, float* __restrict__ g, int* __restrict__ done,
    const float* __restrict__ Wv, const float* __restrict__ bv,
    float* __restrict__ out, int N) {
    __shared__ float part[4][64];
    __shared__ int amlast;
    int c = threadIdx.x & 63;
    int r = threadIdx.x >> 6;
    float acc = 0.f;
    for (long long n = (long long)blockIdx.x * 4 + r; n < N; n += (long long)gridDim.x * 4)
        acc += x[n * 64 + c];
    part[r][c] = acc;
    __syncthreads();
    if (r == 0) {
        float v = part[0][c] + part[1][c] + part[2][c] + part[3][c];
        atomAddF(&g[c], v);
    }
    __threadfence();
    if (threadIdx.x == 0) {
        int t = __hip_atomic_fetch_add(done, 1, __ATOMIC_ACQ_REL, __HIP_MEMORY_SCOPE_AGENT);
        amlast = (t == (int)gridDim.x - 1) ? 1 : 0;
    }
    __syncthreads();
    if (amlast && threadIdx.x < 64) {
        float gc = __hip_atomic_load(&g[threadIdx.x], __ATOMIC_RELAXED, __HIP_MEMORY_SCOPE_AGENT);
        float v = (gc / (float)N) * Wv[threadIdx.x];
        #pragma unroll
        for (int o = 32; o; o >>= 1) v += __shfl_down(v, o);
        if (threadIdx.x == 0) out[0] = v + bv[0];
    }
}

extern "C" void kernel_launch(void* const* d_in, const int* in_sizes, int n_in,
                              void* d_out, int out_size, void* d_ws, size_t ws_size,
                              hipStream_t stream) {
    const float* nf   = (const float*)d_in[0];
    const float* act  = (const float*)d_in[1];
    const int*   ei   = (const int*)d_in[2];
    const float* Wemb = (const float*)d_in[3];
    const float* bemb = (const float*)d_in[4];
    const float* W1   = (const float*)d_in[5];
    const float* as1  = (const float*)d_in[6];
    const float* ad1  = (const float*)d_in[7];
    const float* b1   = (const float*)d_in[8];
    const float* W2   = (const float*)d_in[9];
    const float* as2  = (const float*)d_in[10];
    const float* ad2  = (const float*)d_in[11];
    const float* b2   = (const float*)d_in[12];
    const float* Wv   = (const float*)d_in[13];
    const float* bv   = (const float*)d_in[14];
    float* out = (float*)d_out;

    const int N = in_sizes[0] / FEAT;
    const int E = in_sizes[2] / 2;
    const int ET = E + N;
    const int* srcp = ei;
    const int* dstp = ei + E;
    const int NB = (N + 255) / 256;
    const int HB = (ET + 255) / 256;

    // ---- workspace layout ----
    char* ws = (char*)d_ws;
    unsigned short* Xh = (unsigned short*)ws;                         // N*128 bf16
    unsigned short* Xl = Xh + (size_t)N * 128;                        // N*128 bf16
    __hip_bfloat16* h1b   = (__hip_bfloat16*)(Xl + (size_t)N * 128);  // N*256 bf16
    __hip_bfloat16* out1b = h1b + (size_t)N * 256;                    // N*256 bf16
    float* a_s  = (float*)(out1b + (size_t)N * 256);                  // N*4 f32
    float* a_d  = a_s + (size_t)N * 4;                                // N*4 f32
    __hip_bfloat16* h2b = (__hip_bfloat16*)(a_d + (size_t)N * 4);     // N*64 bf16
    float* out2 = (float*)(h2b + (size_t)N * 64);                     // N*64 f32
    float* g    = out2 + (size_t)N * 64;                              // 64
    __hip_bfloat16* w2t = (__hip_bfloat16*)(g + 64);                  // 64*256 bf16
    unsigned short* wfh = (unsigned short*)(w2t + 64 * 256);          // 256*128
    unsigned short* wfl = wfh + 256 * 128;                            // 256*128
    float* bfused = (float*)(wfl + 256 * 128);                        // 256 f32
    // CSR in dedicated region (no aliasing -> hist can overlap gemm1)
    int* cnt  = (int*)(bfused + 256);  // N
    int* cur  = cnt + N;               // N   (adjacent -> single memset)
    int* offl = cur + N;               // N   (block-local exclusive prefix)
    int* off  = offl + N;              // N+1 (finalized)
    int* perm = off + N + 1;           // ET
    int* bsum = perm + ET;             // NB
    int* bpre = bsum + NB;             // NB+1
    int* done = bpre + NB + 1;         // 1

    (void)ws_size; (void)n_in; (void)out_size;

    // ---- zero cnt+cur up front ----
    hipMemsetAsync(cnt, 0, (size_t)2 * N * sizeof(int), stream);

    // ---- merged prep: X split-bf16 (8 elems/thread) + fused W1 + W2 ----
    const int XB = ((N * 16) + 255) / 256;
    prep_all<<<XB + 129 + 64, 256, 0, stream>>>(nf, act, Xh, Xl, N, XB,
                                                Wemb, bemb, W1, wfh, wfl, bfused,
                                                W2, w2t);

    // ---- GAT layer 1 GEMM (MFMA, A-prefetch pipelined) + overlapped hist ----
    const int GB = 1024;
    gemm1_hist<<<GB + HB, 256, 0, stream>>>(Xh, Xl, wfh, wfl, bfused,
                                            as1, ad1, h1b, a_s, a_d, N,
                                            dstp, cnt, E, ET, GB);

    // ---- CSR scan + scatter ----
    scan_blocks<<<NB, 256, 0, stream>>>(cnt, offl, bsum, N);
    scan_tops<<<1, 256, 0, stream>>>(bsum, bpre, NB, g, done);
    {
        const int FB = (N + 1 + 255) / 256;
        scatter_fin<<<HB + FB, 256, 0, stream>>>(srcp, dstp, offl, bpre, cur,
                                                 perm, off, E, ET, N, NB, HB);
    }

    // ---- GAT layer 1: fused softmax + aggregate + bias + relu (bf16 out) ----
    fused_gat4<<<(N + 3) / 4, 256, 0, stream>>>(off, perm, a_s, a_d, h1b, b1, out1b, N);

    // ---- GAT layer 2: MFMA GEMM (B-in-register) + scores, then fused aggregate ----
    gemm2_mfma_w<<<512, 256, 0, stream>>>(out1b, w2t, as2, ad2, h2b, a_s, a_d, N);
    fused_gat1<<<(N + 3) / 4, 256, 0, stream>>>(off, perm, a_s, a_d, h2b, b2, out2, N);

    // ---- readout (merged colsum + final) ----
    colsum_final<<<512, 256, 0, stream>>>(out2, g, done, Wv, bv, out, N);
}

// Round 22
// 284.853 us; speedup vs baseline: 1.0245x; 1.0001x over previous
//
#include <hip/hip_runtime.h>
#include <hip/hip_bf16.h>
#include <math.h>

#define FEAT 96
#define ACTF 32

using frag8 = __attribute__((ext_vector_type(8))) short;   // 8 bf16 (4 VGPRs)
using f32x4 = __attribute__((ext_vector_type(4))) float;

__device__ __forceinline__ float lrelu(float x) { return x >= 0.f ? x : 0.2f * x; }
__device__ __forceinline__ void atomAddF(float* p, float v) {
    __hip_atomic_fetch_add(p, v, __ATOMIC_RELAXED, __HIP_MEMORY_SCOPE_AGENT);
}
__device__ __forceinline__ float expc(float x) { return __expf(fminf(x, 60.f)); }
__device__ __forceinline__ unsigned short f2bf(float f) {
    __hip_bfloat16 h = __float2bfloat16(f);
    return *(unsigned short*)&h;
}
__device__ __forceinline__ float bf2f(unsigned short u) {
    return __uint_as_float((unsigned)u << 16);
}
__device__ __forceinline__ float bflo(unsigned u) { return __uint_as_float(u << 16); }
__device__ __forceinline__ float bfhi(unsigned u) { return __uint_as_float(u & 0xffff0000u); }

// ---------- merged prep: xprep (vectorized, 8 elems/thread) + W1-fuse + W2 ----------
__global__ __launch_bounds__(256) void prep_all(
    const float* __restrict__ nf, const float* __restrict__ act,
    unsigned short* __restrict__ Xh, unsigned short* __restrict__ Xl,
    int N, int xb,
    const float* __restrict__ Wemb, const float* __restrict__ bemb,
    const float* __restrict__ W1,
    unsigned short* __restrict__ wfh, unsigned short* __restrict__ wfl,
    float* __restrict__ bfused,
    const float* __restrict__ W2, __hip_bfloat16* __restrict__ w2t) {
    int b = blockIdx.x;
    if (b < xb) {
        int gid = b * 256 + threadIdx.x;
        int node = gid >> 4, sub = gid & 15;
        if (node < N) {
            int k0 = sub * 8;
            float4 v0, v1;
            if (k0 < FEAT) {
                const float4* p = (const float4*)(nf + (size_t)node * FEAT + k0);
                v0 = p[0]; v1 = p[1];
            } else {
                const float4* p = (const float4*)(act + (size_t)node * ACTF + (k0 - FEAT));
                v0 = p[0]; v1 = p[1];
            }
            float vv[8] = {v0.x, v0.y, v0.z, v0.w, v1.x, v1.y, v1.z, v1.w};
            uint4 ph, pl;
            unsigned hs[8], ls[8];
            #pragma unroll
            for (int j = 0; j < 8; ++j) {
                unsigned short h = f2bf(vv[j]);
                hs[j] = h;
                ls[j] = f2bf(vv[j] - bf2f(h));
            }
            ph.x = hs[0] | (hs[1] << 16); ph.y = hs[2] | (hs[3] << 16);
            ph.z = hs[4] | (hs[5] << 16); ph.w = hs[6] | (hs[7] << 16);
            pl.x = ls[0] | (ls[1] << 16); pl.y = ls[2] | (ls[3] << 16);
            pl.z = ls[4] | (ls[5] << 16); pl.w = ls[6] | (ls[7] << 16);
            size_t idx = (size_t)node * 128 + k0;
            *(uint4*)(Xh + idx) = ph;
            *(uint4*)(Xl + idx) = pl;
        }
        return;
    }
    b -= xb;
    if (b < 129) {
        int k = b, c = threadIdx.x;
        if (k < 128) {
            float s = 0.f;
            for (int j = 0; j < 64; ++j) s = fmaf(Wemb[k * 64 + j], W1[j * 256 + c], s);
            unsigned short h = f2bf(s);
            wfh[(size_t)c * 128 + k] = h;
            wfl[(size_t)c * 128 + k] = f2bf(s - bf2f(h));
        } else {
            float s = 0.f;
            for (int j = 0; j < 64; ++j) s = fmaf(bemb[j], W1[j * 256 + c], s);
            bfused[c] = s;
        }
        return;
    }
    b -= 129;
    int i = b * 256 + threadIdx.x;
    int k = i >> 6, c = i & 63;
    w2t[(size_t)c * 256 + k] = __float2bfloat16(W2[i]);
}

// ---------- GEMM1 via MFMA + merged hist; A software-pipelined ----------
// Blocks [0,gb): split-bf16 MFMA GEMM, B-in-register, ct split by wave,
//   with next-tile A prefetch hidden under current tile's compute.
// Blocks [gb,..): edge histogram (independent data; overlaps GEMM).
__global__ __launch_bounds__(256, 2) void gemm1_hist(
    const unsigned short* __restrict__ Xh, const unsigned short* __restrict__ Xl,
    const unsigned short* __restrict__ wfh, const unsigned short* __restrict__ wfl,
    const float* __restrict__ bfused, const float* __restrict__ att_s,
    const float* __restrict__ att_d, __hip_bfloat16* __restrict__ h1b,
    float* __restrict__ a_s, float* __restrict__ a_d, int N,
    const int* __restrict__ dstp, int* __restrict__ cnt, int E, int ET, int gb) {
    if (blockIdx.x >= gb) {
        int e = (blockIdx.x - gb) * 256 + threadIdx.x;
        if (e < ET) {
            int d = (e < E) ? dstp[e] : (e - E);
            atomicAdd(&cnt[d], 1);
        }
        return;
    }
    int w = threadIdx.x >> 6, l = threadIdx.x & 63;
    int r16 = l & 15, kg = l >> 4;
    frag8 bh[4][4], bl[4][4];
    #pragma unroll
    for (int c = 0; c < 4; ++c) {
        int ct = w * 4 + c;
        const short* bhp = (const short*)wfh + (size_t)(ct * 16 + r16) * 128 + kg * 8;
        const short* blp = (const short*)wfl + (size_t)(ct * 16 + r16) * 128 + kg * 8;
        #pragma unroll
        for (int ks = 0; ks < 4; ++ks) {
            bh[c][ks] = *(const frag8*)(bhp + ks * 32);
            bl[c][ks] = *(const frag8*)(blp + ks * 32);
        }
    }
    float biasv[4], awv[4], dwv[4];
    #pragma unroll
    for (int c = 0; c < 4; ++c) {
        int ch = w * 64 + c * 16 + r16;
        biasv[c] = bfused[ch];
        awv[c] = att_s[ch];
        dwv[c] = att_d[ch];
    }
    int ntiles = (N + 15) >> 4;
    int tile = blockIdx.x;
    if (tile >= ntiles) return;
    frag8 ah[4], al[4];
    {   // prologue A-load
        int arow = tile * 16 + r16; if (arow >= N) arow = N - 1;
        const short* ahp = (const short*)Xh + (size_t)arow * 128 + kg * 8;
        const short* alp = (const short*)Xl + (size_t)arow * 128 + kg * 8;
        #pragma unroll
        for (int ks = 0; ks < 4; ++ks) {
            ah[ks] = *(const frag8*)(ahp + ks * 32);
            al[ks] = *(const frag8*)(alp + ks * 32);
        }
    }
    for (; tile < ntiles; tile += gb) {
        int nb = tile * 16;
        // prefetch next tile's A while this tile computes
        frag8 nah[4], nal[4];
        int ntile = tile + gb;
        if (ntile < ntiles) {
            int arow = ntile * 16 + r16; if (arow >= N) arow = N - 1;
            const short* ahp = (const short*)Xh + (size_t)arow * 128 + kg * 8;
            const short* alp = (const short*)Xl + (size_t)arow * 128 + kg * 8;
            #pragma unroll
            for (int ks = 0; ks < 4; ++ks) {
                nah[ks] = *(const frag8*)(ahp + ks * 32);
                nal[ks] = *(const frag8*)(alp + ks * 32);
            }
        }
        float s_s[4] = {0.f, 0.f, 0.f, 0.f}, s_d[4] = {0.f, 0.f, 0.f, 0.f};
        #pragma unroll
        for (int c = 0; c < 4; ++c) {
            f32x4 acc = (f32x4){0.f, 0.f, 0.f, 0.f};
            #pragma unroll
            for (int ks = 0; ks < 4; ++ks) {
                acc = __builtin_amdgcn_mfma_f32_16x16x32_bf16(ah[ks], bh[c][ks], acc, 0, 0, 0);
                acc = __builtin_amdgcn_mfma_f32_16x16x32_bf16(al[ks], bh[c][ks], acc, 0, 0, 0);
                acc = __builtin_amdgcn_mfma_f32_16x16x32_bf16(ah[ks], bl[c][ks], acc, 0, 0, 0);
            }
            int ch = w * 64 + c * 16 + r16;
            #pragma unroll
            for (int r = 0; r < 4; ++r) {
                int node = nb + kg * 4 + r;
                float v = acc[r] + biasv[c];
                if (node < N) h1b[(size_t)node * 256 + ch] = __float2bfloat16(v);
                s_s[r] = fmaf(v, awv[c], s_s[r]);
                s_d[r] = fmaf(v, dwv[c], s_d[r]);
            }
        }
        #pragma unroll
        for (int r = 0; r < 4; ++r) {
            float vs = s_s[r], vd = s_d[r];
            #pragma unroll
            for (int o = 1; o < 16; o <<= 1) {
                vs += __shfl_xor(vs, o);
                vd += __shfl_xor(vd, o);
            }
            int node = nb + kg * 4 + r;
            if (r16 == 0 && node < N) {
                a_s[(size_t)node * 4 + w] = vs;
                a_d[(size_t)node * 4 + w] = vd;
            }
        }
        #pragma unroll
        for (int ks = 0; ks < 4; ++ks) { ah[ks] = nah[ks]; al[ks] = nal[ks]; }
    }
}

// ---------- GEMM2 via MFMA: B-in-register, grid-stride ----------
__global__ __launch_bounds__(256, 2) void gemm2_mfma_w(
    const __hip_bfloat16* __restrict__ out1b, const __hip_bfloat16* __restrict__ w2t,
    const float* __restrict__ att_s, const float* __restrict__ att_d,
    __hip_bfloat16* __restrict__ h2b, float* __restrict__ a_s, float* __restrict__ a_d,
    int N) {
    int w = threadIdx.x >> 6, l = threadIdx.x & 63;
    int r16 = l & 15, kg = l >> 4;
    const short* B = (const short*)w2t;
    frag8 b[4][8];
    #pragma unroll
    for (int ct = 0; ct < 4; ++ct) {
        const short* brp = B + (size_t)(ct * 16 + r16) * 256 + kg * 8;
        #pragma unroll
        for (int ks = 0; ks < 8; ++ks)
            b[ct][ks] = *(const frag8*)(brp + ks * 32);
    }
    float awv[4], dwv[4];
    #pragma unroll
    for (int ct = 0; ct < 4; ++ct) {
        int ch = ct * 16 + r16;
        awv[ct] = att_s[ch];
        dwv[ct] = att_d[ch];
    }
    const short* A = (const short*)out1b;
    int ntiles = (N + 15) >> 4;
    for (int tile = blockIdx.x * 4 + w; tile < ntiles; tile += gridDim.x * 4) {
        int nb = tile * 16;
        int arow = nb + r16; if (arow >= N) arow = N - 1;
        const short* arp = A + (size_t)arow * 256 + kg * 8;
        frag8 a[8];
        #pragma unroll
        for (int ks = 0; ks < 8; ++ks) a[ks] = *(const frag8*)(arp + ks * 32);
        float s_s[4] = {0.f, 0.f, 0.f, 0.f}, s_d[4] = {0.f, 0.f, 0.f, 0.f};
        #pragma unroll
        for (int ct = 0; ct < 4; ++ct) {
            f32x4 acc = (f32x4){0.f, 0.f, 0.f, 0.f};
            #pragma unroll
            for (int ks = 0; ks < 8; ++ks)
                acc = __builtin_amdgcn_mfma_f32_16x16x32_bf16(a[ks], b[ct][ks], acc, 0, 0, 0);
            int ch = ct * 16 + r16;
            #pragma unroll
            for (int r = 0; r < 4; ++r) {
                int node = nb + kg * 4 + r;
                float v = acc[r];
                if (node < N) h2b[(size_t)node * 64 + ch] = __float2bfloat16(v);
                s_s[r] = fmaf(v, awv[ct], s_s[r]);
                s_d[r] = fmaf(v, dwv[ct], s_d[r]);
            }
        }
        #pragma unroll
        for (int r = 0; r < 4; ++r) {
            #pragma unroll
            for (int o = 1; o < 16; o <<= 1) {
                s_s[r] += __shfl_xor(s_s[r], o);
                s_d[r] += __shfl_xor(s_d[r], o);
            }
            int node = nb + kg * 4 + r;
            if (r16 == 0 && node < N) { a_s[node] = s_s[r]; a_d[node] = s_d[r]; }
        }
    }
}

// ---------- hierarchical scan ----------
__global__ __launch_bounds__(256) void scan_blocks(
    const int* __restrict__ cnt, int* __restrict__ offl, int* __restrict__ bsum, int n) {
    int b = blockIdx.x, t = threadIdx.x;
    int i = b * 256 + t;
    int v = (i < n) ? cnt[i] : 0;
    int lane = t & 63, w = t >> 6;
    int x = v;
    #pragma unroll
    for (int o = 1; o < 64; o <<= 1) {
        int y = __shfl_up(x, o);
        if (lane >= o) x += y;
    }
    __shared__ int wtot[4];
    if (lane == 63) wtot[w] = x;
    __syncthreads();
    int add = 0;
    #pragma unroll
    for (int j = 0; j < 4; ++j) if (j < w) add += wtot[j];
    int incl = x + add;
    if (i < n) offl[i] = incl - v;    // exclusive prefix within block
    if (t == 255) bsum[b] = incl;
}

// also zeroes g[64] + done counter for colsum_final
__global__ __launch_bounds__(256) void scan_tops(
    const int* __restrict__ bsum, int* __restrict__ bpre, int nb,
    float* __restrict__ g, int* __restrict__ done) {
    int t = threadIdx.x;
    int v = (t < nb) ? bsum[t] : 0;
    int lane = t & 63, w = t >> 6;
    int x = v;
    #pragma unroll
    for (int o = 1; o < 64; o <<= 1) {
        int y = __shfl_up(x, o);
        if (lane >= o) x += y;
    }
    __shared__ int wtot[4];
    if (lane == 63) wtot[w] = x;
    __syncthreads();
    int add = 0;
    #pragma unroll
    for (int j = 0; j < 4; ++j) if (j < w) add += wtot[j];
    if (t < nb) bpre[t] = x + add - v;
    if (t == 255) bpre[nb] = x + add;
    if (t < 64) g[t] = 0.f;
    if (t == 64) *done = 0;
}

// ---------- scatter + off-finalize (merged; independent block roles) ----------
__global__ void scatter_fin(const int* __restrict__ src, const int* __restrict__ dst,
                            const int* __restrict__ offl, const int* __restrict__ bpre,
                            int* __restrict__ cur, int* __restrict__ perm,
                            int* __restrict__ off, int E, int ET, int n, int nb, int sb) {
    if (blockIdx.x < sb) {
        int e = blockIdx.x * 256 + threadIdx.x;
        if (e >= ET) return;
        int s = (e < E) ? src[e] : (e - E);
        int d = (e < E) ? dst[e] : (e - E);
        int r = atomicAdd(&cur[d], 1);
        perm[offl[d] + bpre[d >> 8] + r] = s;
    } else {
        int i = (blockIdx.x - sb) * 256 + threadIdx.x;
        if (i < n) off[i] = offl[i] + bpre[i >> 8];
        if (i == n) off[n] = bpre[nb];
    }
}

// ---------- fused GAT layer 1 (H=4): single pass, den fused into staging ----------
__global__ __launch_bounds__(256) void fused_gat4(
    const int* __restrict__ off, const int* __restrict__ perm,
    const float* __restrict__ a_s, const float* __restrict__ a_d,
    const __hip_bfloat16* __restrict__ h1b, const float* __restrict__ bias,
    __hip_bfloat16* __restrict__ out1b, int N) {
    __shared__ float exls[4][4][68];
    __shared__ unsigned idxls[4][64];
    int w = threadIdx.x >> 6, l = threadIdx.x & 63;
    int d = blockIdx.x * 4 + w;
    if (d >= N) return;
    int lo = off[d], hi = off[d + 1];
    const float4* as4 = (const float4*)a_s;
    float4 ad = ((const float4*)a_d)[d];
    int eg = l >> 5;
    int li = l & 31;
    int gh = li >> 3;
    const char* hb = (const char*)h1b;
    unsigned laneoff = (unsigned)li * 16u;
    float acc[8] = {0.f, 0.f, 0.f, 0.f, 0.f, 0.f, 0.f, 0.f};
    float dx = 0.f, dy = 0.f, dz = 0.f, dw = 0.f;
    for (int base = lo; base < hi; base += 64) {
        int e = base + l;
        bool valid = e < hi;
        int s = valid ? perm[e] : 0;
        float4 a = as4[s];
        float e0 = valid ? expc(lrelu(a.x + ad.x)) : 0.f;
        float e1 = valid ? expc(lrelu(a.y + ad.y)) : 0.f;
        float e2 = valid ? expc(lrelu(a.z + ad.z)) : 0.f;
        float e3 = valid ? expc(lrelu(a.w + ad.w)) : 0.f;
        dx += e0; dy += e1; dz += e2; dw += e3;
        exls[w][0][l] = e0;
        exls[w][1][l] = e1;
        exls[w][2][l] = e2;
        exls[w][3][l] = e3;
        idxls[w][l] = valid ? (unsigned)s * 512u : 0u;
        int n = min(64, hi - base);
        #pragma unroll 2
        for (int i = 0; i < n; i += 2) {
            int ii = i + eg;
            float ex = exls[w][gh][ii];
            unsigned voff = idxls[w][ii] + laneoff;
            uint4 v = *(const uint4*)(hb + voff);
            acc[0] = fmaf(ex, bflo(v.x), acc[0]);
            acc[1] = fmaf(ex, bfhi(v.x), acc[1]);
            acc[2] = fmaf(ex, bflo(v.y), acc[2]);
            acc[3] = fmaf(ex, bfhi(v.y), acc[3]);
            acc[4] = fmaf(ex, bflo(v.z), acc[4]);
            acc[5] = fmaf(ex, bfhi(v.z), acc[5]);
            acc[6] = fmaf(ex, bflo(v.w), acc[6]);
            acc[7] = fmaf(ex, bfhi(v.w), acc[7]);
        }
    }
    #pragma unroll
    for (int o = 32; o; o >>= 1) {
        dx += __shfl_xor(dx, o); dy += __shfl_xor(dy, o);
        dz += __shfl_xor(dz, o); dw += __shfl_xor(dw, o);
    }
    float rr = 1.f / ((gh == 0 ? dx : gh == 1 ? dy : gh == 2 ? dz : dw) + 1e-16f);
    #pragma unroll
    for (int j = 0; j < 8; ++j) acc[j] += __shfl_xor(acc[j], 32);
    if (eg == 0) {
        float4 b0 = ((const float4*)bias)[li * 2];
        float4 b1 = ((const float4*)bias)[li * 2 + 1];
        uint4 pk;
        pk.x = (unsigned)f2bf(fmaxf(fmaf(acc[0], rr, b0.x), 0.f))
             | ((unsigned)f2bf(fmaxf(fmaf(acc[1], rr, b0.y), 0.f)) << 16);
        pk.y = (unsigned)f2bf(fmaxf(fmaf(acc[2], rr, b0.z), 0.f))
             | ((unsigned)f2bf(fmaxf(fmaf(acc[3], rr, b0.w), 0.f)) << 16);
        pk.z = (unsigned)f2bf(fmaxf(fmaf(acc[4], rr, b1.x), 0.f))
             | ((unsigned)f2bf(fmaxf(fmaf(acc[5], rr, b1.y), 0.f)) << 16);
        pk.w = (unsigned)f2bf(fmaxf(fmaf(acc[6], rr, b1.z), 0.f))
             | ((unsigned)f2bf(fmaxf(fmaf(acc[7], rr, b1.w), 0.f)) << 16);
        ((uint4*)(out1b + (size_t)d * 256))[li] = pk;
    }
}

// ---------- fused GAT layer 2 (H=1): single pass, den fused into staging ----------
__global__ __launch_bounds__(256) void fused_gat1(
    const int* __restrict__ off, const int* __restrict__ perm,
    const float* __restrict__ a_s, const float* __restrict__ a_d,
    const __hip_bfloat16* __restrict__ h2b, const float* __restrict__ bias,
    float* __restrict__ out2, int N) {
    __shared__ float exls1[4][64];
    __shared__ unsigned idxls1[4][64];
    int w = threadIdx.x >> 6, l = threadIdx.x & 63;
    int d = blockIdx.x * 4 + w;
    if (d >= N) return;
    int lo = off[d], hi = off[d + 1];
    float add = a_d[d];
    int eg = l >> 4;
    int li = l & 15;
    const char* hb = (const char*)h2b;
    unsigned laneoff = (unsigned)li * 8u;
    float den = 0.f;
    float acc0 = 0.f, acc1 = 0.f, acc2 = 0.f, acc3 = 0.f;
    for (int base = lo; base < hi; base += 64) {
        int e = base + l;
        bool valid = e < hi;
        int s = valid ? perm[e] : 0;
        float ex = valid ? expc(lrelu(a_s[s] + add)) : 0.f;
        den += ex;
        exls1[w][l] = ex;
        idxls1[w][l] = valid ? (unsigned)s * 128u : 0u;
        int n = min(64, hi - base);
        #pragma unroll 4
        for (int i = 0; i < n; i += 4) {
            int ii = i + eg;
            float exx = exls1[w][ii];
            unsigned voff = idxls1[w][ii] + laneoff;
            uint2 v = *(const uint2*)(hb + voff);
            acc0 = fmaf(exx, bflo(v.x), acc0);
            acc1 = fmaf(exx, bfhi(v.x), acc1);
            acc2 = fmaf(exx, bflo(v.y), acc2);
            acc3 = fmaf(exx, bfhi(v.y), acc3);
        }
    }
    #pragma unroll
    for (int o = 32; o; o >>= 1) den += __shfl_xor(den, o);
    float rr = 1.f / (den + 1e-16f);
    #pragma unroll
    for (int o = 16; o < 64; o <<= 1) {
        acc0 += __shfl_xor(acc0, o);
        acc1 += __shfl_xor(acc1, o);
        acc2 += __shfl_xor(acc2, o);
        acc3 += __shfl_xor(acc3, o);
    }
    if (eg == 0 && (l >> 4) == 0) {
        const float4* b4 = (const float4*)bias;
        float4 bv = b4[li];
        float4 o4;
        o4.x = fmaxf(fmaf(acc0, rr, bv.x), 0.f);
        o4.y = fmaxf(fmaf(acc1, rr, bv.y), 0.f);
        o4.z = fmaxf(fmaf(acc2, rr, bv.z), 0.f);
        o4.w = fmaxf(fmaf(acc3, rr, bv.w), 0.f);
        ((float4*)(out2 + (size_t)d * 64))[li] = o4;
    }
}

// ---------- column sum + final dot (merged via done-counter) ----------
__global__ __launch_bounds__(256) void colsum_final(
    const float* __restrict__ x, float* __restrict__ g, int* __restrict__ done,
    const float* __restrict__ Wv, const float* __restrict__ bv,
    float* __restrict__ out, int N) {
    __shared__ float part[4][64];
    __shared__ int amlast;
    int c = threadIdx.x & 63;
    int r = threadIdx.x >> 6;
    float acc = 0.f;
    for (long long n = (long long)blockIdx.x * 4 + r; n < N; n += (long long)gridDim.x * 4)
        acc += x[n * 64 + c];
    part[r][c] = acc;
    __syncthreads();
    if (r == 0) {
        float v = part[0][c] + part[1][c] + part[2][c] + part[3][c];
        atomAddF(&g[c], v);
    }
    __threadfence();
    if (threadIdx.x == 0) {
        int t = __hip_atomic_fetch_add(done, 1, __ATOMIC_ACQ_REL, __HIP_MEMORY_SCOPE_AGENT);
        amlast = (t == (int)gridDim.x - 1) ? 1 : 0;
    }
    __syncthreads();
    if (amlast && threadIdx.x < 64) {
        float gc = __hip_atomic_load(&g[threadIdx.x], __ATOMIC_RELAXED, __HIP_MEMORY_SCOPE_AGENT);
        float v = (gc / (float)N) * Wv[threadIdx.x];
        #pragma unroll
        for (int o = 32; o; o >>= 1) v += __shfl_down(v, o);
        if (threadIdx.x == 0) out[0] = v + bv[0];
    }
}

extern "C" void kernel_launch(void* const* d_in, const int* in_sizes, int n_in,
                              void* d_out, int out_size, void* d_ws, size_t ws_size,
                              hipStream_t stream) {
    const float* nf   = (const float*)d_in[0];
    const float* act  = (const float*)d_in[1];
    const int*   ei   = (const int*)d_in[2];
    const float* Wemb = (const float*)d_in[3];
    const float* bemb = (const float*)d_in[4];
    const float* W1   = (const float*)d_in[5];
    const float* as1  = (const float*)d_in[6];
    const float* ad1  = (const float*)d_in[7];
    const float* b1   = (const float*)d_in[8];
    const float* W2   = (const float*)d_in[9];
    const float* as2  = (const float*)d_in[10];
    const float* ad2  = (const float*)d_in[11];
    const float* b2   = (const float*)d_in[12];
    const float* Wv   = (const float*)d_in[13];
    const float* bv   = (const float*)d_in[14];
    float* out = (float*)d_out;

    const int N = in_sizes[0] / FEAT;
    const int E = in_sizes[2] / 2;
    const int ET = E + N;
    const int* srcp = ei;
    const int* dstp = ei + E;
    const int NB = (N + 255) / 256;
    const int HB = (ET + 255) / 256;

    // ---- workspace layout ----
    char* ws = (char*)d_ws;
    unsigned short* Xh = (unsigned short*)ws;                         // N*128 bf16
    unsigned short* Xl = Xh + (size_t)N * 128;                        // N*128 bf16
    __hip_bfloat16* h1b   = (__hip_bfloat16*)(Xl + (size_t)N * 128);  // N*256 bf16
    __hip_bfloat16* out1b = h1b + (size_t)N * 256;                    // N*256 bf16
    float* a_s  = (float*)(out1b + (size_t)N * 256);                  // N*4 f32
    float* a_d  = a_s + (size_t)N * 4;                                // N*4 f32
    __hip_bfloat16* h2b = (__hip_bfloat16*)(a_d + (size_t)N * 4);     // N*64 bf16
    float* out2 = (float*)(h2b + (size_t)N * 64);                     // N*64 f32
    float* g    = out2 + (size_t)N * 64;                              // 64
    __hip_bfloat16* w2t = (__hip_bfloat16*)(g + 64);                  // 64*256 bf16
    unsigned short* wfh = (unsigned short*)(w2t + 64 * 256);          // 256*128
    unsigned short* wfl = wfh + 256 * 128;                            // 256*128
    float* bfused = (float*)(wfl + 256 * 128);                        // 256 f32
    // CSR in dedicated region (no aliasing -> hist can overlap gemm1)
    int* cnt  = (int*)(bfused + 256);  // N
    int* cur  = cnt + N;               // N   (adjacent -> single memset)
    int* offl = cur + N;               // N   (block-local exclusive prefix)
    int* off  = offl + N;              // N+1 (finalized)
    int* perm = off + N + 1;           // ET
    int* bsum = perm + ET;             // NB
    int* bpre = bsum + NB;             // NB+1
    int* done = bpre + NB + 1;         // 1

    (void)ws_size; (void)n_in; (void)out_size;

    // ---- zero cnt+cur up front ----
    hipMemsetAsync(cnt, 0, (size_t)2 * N * sizeof(int), stream);

    // ---- merged prep: X split-bf16 (8 elems/thread) + fused W1 + W2 ----
    const int XB = ((N * 16) + 255) / 256;
    prep_all<<<XB + 129 + 64, 256, 0, stream>>>(nf, act, Xh, Xl, N, XB,
                                                Wemb, bemb, W1, wfh, wfl, bfused,
                                                W2, w2t);

    // ---- GAT layer 1 GEMM (MFMA, A-prefetch pipelined) + overlapped hist ----
    const int GB = 1024;
    gemm1_hist<<<GB + HB, 256, 0, stream>>>(Xh, Xl, wfh, wfl, bfused,
                                            as1, ad1, h1b, a_s, a_d, N,
                                            dstp, cnt, E, ET, GB);

    // ---- CSR scan + scatter ----
    scan_blocks<<<NB, 256, 0, stream>>>(cnt, offl, bsum, N);
    scan_tops<<<1, 256, 0, stream>>>(bsum, bpre, NB, g, done);
    {
        const int FB = (N + 1 + 255) / 256;
        scatter_fin<<<HB + FB, 256, 0, stream>>>(srcp, dstp, offl, bpre, cur,
                                                 perm, off, E, ET, N, NB, HB);
    }

    // ---- GAT layer 1: fused softmax + aggregate + bias + relu (bf16 out) ----
    fused_gat4<<<(N + 3) / 4, 256, 0, stream>>>(off, perm, a_s, a_d, h1b, b1, out1b, N);

    // ---- GAT layer 2: MFMA GEMM (B-in-register) + scores, then fused aggregate ----
    gemm2_mfma_w<<<512, 256, 0, stream>>>(out1b, w2t, as2, ad2, h2b, a_s, a_d, N);
    fused_gat1<<<(N + 3) / 4, 256, 0, stream>>>(off, perm, a_s, a_d, h2b, b2, out2, N);

    // ---- readout (merged colsum + final) ----
    colsum_final<<<512, 256, 0, stream>>>(out2, g, done, Wv, bv, out, N);
}